// Round 6
// baseline (61.885 us; speedup 1.0000x reference)
//
#include <hip/hip_runtime.h>

// MoE routing: softmax(logits[T,64]) -> top-2 (indices, values) per token.
// Output layout (floats): [0,2T) = indices as floats, [2T,4T) = prob values.
//
// 4 lanes/token; lane owns 16 elems as 4 interleaved 16B vectors (load inst k
// reads 64 contiguous bytes per token-group -> perfect coalescing).
// Pure streaming (no reuse): non-temporal load/store hints keep the 256 MiB
// input stream from thrashing L2/L3 against the write stream.
// NOTE: __builtin_nontemporal_* requires native clang vector types
// (ext_vector_type), not HIP_vector_type float4/float2 (r5 compile fail).
// Top-2 via in-register sequential scan (exact lax.top_k tie semantics),
// 2 cross-lane merge stages. exp via v_exp_f32 with fma-folded max-sub.
// r4 post-mortem: manual software pipelining neutral (TLP already hides
// latency at 32 waves/CU) -- simple grid-stride loop retained.

constexpr int E = 64;

typedef float f32x4 __attribute__((ext_vector_type(4)));
typedef float f32x2 __attribute__((ext_vector_type(2)));

__global__ __launch_bounds__(256) void moe_route_kernel(
    const float* __restrict__ logits,
    float* __restrict__ out,
    int T, int nGroups)
{
    const int tid = blockIdx.x * blockDim.x + threadIdx.x;
    const int g0  = tid >> 2;          // token-group id (4 lanes per token)
    const int sub = tid & 3;

    float* __restrict__ idx_out = out;
    float* __restrict__ val_out = out + 2ull * (unsigned long long)T;

    for (int row = g0; row < T; row += nGroups) {
        const float* rp = logits + (size_t)row * E + sub * 4;
        const f32x4 c0 = __builtin_nontemporal_load(
            reinterpret_cast<const f32x4*>(rp));
        const f32x4 c1 = __builtin_nontemporal_load(
            reinterpret_cast<const f32x4*>(rp + 16));
        const f32x4 c2 = __builtin_nontemporal_load(
            reinterpret_cast<const f32x4*>(rp + 32));
        const f32x4 c3 = __builtin_nontemporal_load(
            reinterpret_cast<const f32x4*>(rp + 48));

        // ---- in-lane sequential top-2 scan over 16 elems ----
        float b1 = c0.x; int p1l = 0;
        float b2 = -__builtin_inff(); int p2l = 0;
        #define SCAN(v, P) do {                                   \
            const float _v = (v); const bool cc1 = _v > b1;       \
            const bool cc2 = _v > b2;                             \
            const float ob1 = b1; const int op1 = p1l;            \
            b2  = cc1 ? ob1 : (cc2 ? _v  : b2);                   \
            p2l = cc1 ? op1 : (cc2 ? (P) : p2l);                  \
            b1  = cc1 ? _v  : b1;                                 \
            p1l = cc1 ? (P) : p1l;                                \
        } while (0)
        SCAN(c0.y, 1);  SCAN(c0.z, 2);  SCAN(c0.w, 3);
        SCAN(c1.x, 4);  SCAN(c1.y, 5);  SCAN(c1.z, 6);  SCAN(c1.w, 7);
        SCAN(c2.x, 8);  SCAN(c2.y, 9);  SCAN(c2.z, 10); SCAN(c2.w, 11);
        SCAN(c3.x, 12); SCAN(c3.y, 13); SCAN(c3.z, 14); SCAN(c3.w, 15);
        #undef SCAN

        // local position -> global expert index: g = k*16 + sub*4 + c
        int i1 = ((p1l & 0xC) << 2) | (sub << 2) | (p1l & 3);
        int i2 = ((p2l & 0xC) << 2) | (sub << 2) | (p2l & 3);

        // ---- cross-lane top-2 merge: 2 butterfly stages (4 lanes) ----
        #pragma unroll
        for (int mask = 1; mask <= 2; mask <<= 1) {
            const float o1 = __shfl_xor(b1, mask);
            const int   j1 = __shfl_xor(i1, mask);
            const float o2 = __shfl_xor(b2, mask);
            const int   j2 = __shfl_xor(i2, mask);
            if (o1 > b1 || (o1 == b1 && j1 < i1)) {
                float nb2 = b1; int ni2 = i1;
                if (o2 > nb2 || (o2 == nb2 && j2 < ni2)) { nb2 = o2; ni2 = j2; }
                b2 = nb2; i2 = ni2; b1 = o1; i1 = j1;
            } else {
                if (o1 > b2 || (o1 == b2 && j1 < i2)) { b2 = o1; i2 = j1; }
            }
        }

        // ---- softmax denom: exp(x-m) = 2^(fma(x, log2e, -m*log2e)) ----
        const float L2E   = 1.4426950408889634f;
        const float negmL = -b1 * L2E;
        #define EX(v) __builtin_amdgcn_exp2f(fmaf((v), L2E, negmL))
        float s = EX(c0.x) + EX(c0.y) + EX(c0.z) + EX(c0.w)
                + EX(c1.x) + EX(c1.y) + EX(c1.z) + EX(c1.w)
                + EX(c2.x) + EX(c2.y) + EX(c2.z) + EX(c2.w)
                + EX(c3.x) + EX(c3.y) + EX(c3.z) + EX(c3.w);
        s += __shfl_xor(s, 1);
        s += __shfl_xor(s, 2);

        if (sub == 0) {
            const float r   = __builtin_amdgcn_rcpf(s);  // ~1 ulp
            const float pv2 = EX(b2) * r;
            f32x2 iv; iv.x = (float)i1; iv.y = (float)i2;
            f32x2 pv; pv.x = r;         pv.y = pv2;       // p1 = 1/s
            __builtin_nontemporal_store(iv,
                reinterpret_cast<f32x2*>(idx_out + (size_t)row * 2));
            __builtin_nontemporal_store(pv,
                reinterpret_cast<f32x2*>(val_out + (size_t)row * 2));
        }
        #undef EX
    }
}

extern "C" void kernel_launch(void* const* d_in, const int* in_sizes, int n_in,
                              void* d_out, int out_size, void* d_ws, size_t ws_size,
                              hipStream_t stream) {
    const float* logits = (const float*)d_in[0];
    float* out = (float*)d_out;
    const int T = in_sizes[0] / E;   // 1048576

    const int threads = 256;
    const int groupsPerBlock = threads / 4;                 // 64 tokens/block
    int blocks = 2048;                                      // 8 blocks/CU, 32 waves/CU
    const int maxBlocks = (T + groupsPerBlock - 1) / groupsPerBlock;
    if (blocks > maxBlocks) blocks = maxBlocks;
    const int nGroups = blocks * groupsPerBlock;

    moe_route_kernel<<<blocks, threads, 0, stream>>>(logits, out, T, nGroups);
}

// Round 7
// 49.191 us; speedup vs baseline: 1.2581x; 1.2581x over previous
//
#include <hip/hip_runtime.h>

// MoE routing: softmax(logits[T,64]) -> top-2 (indices, values) per token.
// Output layout (floats): [0,2T) = indices as floats, [2T,4T) = prob values.
//
// BEST-MEASURED VARIANT (round 3, 49.4 us = 92% of 6.29 TB/s copy ceiling).
// 4 lanes/token; lane owns 16 elems as 4 interleaved float4s (load inst k
// reads 64 contiguous bytes per token-group -> perfect coalescing).
// Top-2 via in-register sequential scan (exact lax.top_k tie semantics:
// increasing index order + strict '>'), then only 2 cross-lane merge stages.
// Softmax: top-1 IS the row max, p1 = 1/sum, only p2 needs another exp.
//
// Post-mortems baked in:
//  r4: manual software pipelining neutral (-1.6%) -- TLP at 32 waves/CU
//      already hides load latency; reverted.
//  r6: non-temporal hints -25% -- input is exactly L3-sized; nt's
//      no-allocate defeats Infinity-Cache residency across replays; reverted.

constexpr int E = 64;

__global__ __launch_bounds__(256) void moe_route_kernel(
    const float* __restrict__ logits,
    float* __restrict__ out,
    int T, int nGroups)
{
    const int tid = blockIdx.x * blockDim.x + threadIdx.x;
    const int g0  = tid >> 2;          // token-group id (4 lanes per token)
    const int sub = tid & 3;

    float* __restrict__ idx_out = out;
    float* __restrict__ val_out = out + 2ull * (unsigned long long)T;

    for (int row = g0; row < T; row += nGroups) {
        const float* rp = logits + (size_t)row * E + sub * 4;
        const float4 x0 = *reinterpret_cast<const float4*>(rp);
        const float4 x1 = *reinterpret_cast<const float4*>(rp + 16);
        const float4 x2 = *reinterpret_cast<const float4*>(rp + 32);
        const float4 x3 = *reinterpret_cast<const float4*>(rp + 48);

        // ---- in-lane sequential top-2 scan over 16 elems ----
        // local position p = k*4+c (inline consts); increasing global order.
        float b1 = x0.x; int p1l = 0;
        float b2 = -__builtin_inff(); int p2l = 0;
        #define SCAN(v, P) do {                                   \
            const float _v = (v); const bool c1 = _v > b1;        \
            const bool c2 = _v > b2;                              \
            const float ob1 = b1; const int op1 = p1l;            \
            b2  = c1 ? ob1 : (c2 ? _v  : b2);                     \
            p2l = c1 ? op1 : (c2 ? (P) : p2l);                    \
            b1  = c1 ? _v  : b1;                                  \
            p1l = c1 ? (P) : p1l;                                 \
        } while (0)
        SCAN(x0.y, 1);  SCAN(x0.z, 2);  SCAN(x0.w, 3);
        SCAN(x1.x, 4);  SCAN(x1.y, 5);  SCAN(x1.z, 6);  SCAN(x1.w, 7);
        SCAN(x2.x, 8);  SCAN(x2.y, 9);  SCAN(x2.z, 10); SCAN(x2.w, 11);
        SCAN(x3.x, 12); SCAN(x3.y, 13); SCAN(x3.z, 14); SCAN(x3.w, 15);
        #undef SCAN

        // decode local position -> global expert index: g = k*16 + sub*4 + c
        int i1 = ((p1l & 0xC) << 2) | (sub << 2) | (p1l & 3);
        int i2 = ((p2l & 0xC) << 2) | (sub << 2) | (p2l & 3);

        // ---- cross-lane top-2 merge: only 2 butterfly stages (4 lanes) ----
        #pragma unroll
        for (int mask = 1; mask <= 2; mask <<= 1) {
            const float o1 = __shfl_xor(b1, mask);
            const int   j1 = __shfl_xor(i1, mask);
            const float o2 = __shfl_xor(b2, mask);
            const int   j2 = __shfl_xor(i2, mask);
            if (o1 > b1 || (o1 == b1 && j1 < i1)) {
                float nb2 = b1; int ni2 = i1;
                if (o2 > nb2 || (o2 == nb2 && j2 < ni2)) { nb2 = o2; ni2 = j2; }
                b2 = nb2; i2 = ni2; b1 = o1; i1 = j1;
            } else {
                if (o1 > b2 || (o1 == b2 && j1 < i2)) { b2 = o1; i2 = j1; }
            }
        }

        // ---- softmax denominator: s = sum(exp(x - m)), m == b1 (global) ----
        const float m = b1;
        float s = __expf(x0.x - m) + __expf(x0.y - m)
                + __expf(x0.z - m) + __expf(x0.w - m)
                + __expf(x1.x - m) + __expf(x1.y - m)
                + __expf(x1.z - m) + __expf(x1.w - m)
                + __expf(x2.x - m) + __expf(x2.y - m)
                + __expf(x2.z - m) + __expf(x2.w - m)
                + __expf(x3.x - m) + __expf(x3.y - m)
                + __expf(x3.z - m) + __expf(x3.w - m);
        s += __shfl_xor(s, 1);
        s += __shfl_xor(s, 2);

        if (sub == 0) {
            const float r  = __builtin_amdgcn_rcpf(s);  // ~1 ulp
            const float pv1 = r;                         // exp(m-m)/s = 1/s
            const float pv2 = __expf(b2 - m) * r;
            *reinterpret_cast<float2*>(idx_out + (size_t)row * 2) =
                make_float2((float)i1, (float)i2);
            *reinterpret_cast<float2*>(val_out + (size_t)row * 2) =
                make_float2(pv1, pv2);
        }
    }
}

extern "C" void kernel_launch(void* const* d_in, const int* in_sizes, int n_in,
                              void* d_out, int out_size, void* d_ws, size_t ws_size,
                              hipStream_t stream) {
    const float* logits = (const float*)d_in[0];
    float* out = (float*)d_out;
    const int T = in_sizes[0] / E;   // 1048576

    const int threads = 256;
    const int groupsPerBlock = threads / 4;                 // 64 tokens/block
    int blocks = 2048;                                      // 8 blocks/CU, 32 waves/CU
    const int maxBlocks = (T + groupsPerBlock - 1) / groupsPerBlock;
    if (blocks > maxBlocks) blocks = maxBlocks;
    const int nGroups = blocks * groupsPerBlock;

    moe_route_kernel<<<blocks, threads, 0, stream>>>(logits, out, T, nGroups);
}